// Round 6
// baseline (263.989 us; speedup 1.0000x reference)
//
#include <hip/hip_runtime.h>

#define ROWS 4096
#define NCOL 8192
#define WPB 4                       // waves (=rows) per block
#define THREADS (WPB * 64)
#define F4PW (NCOL / 4 / 64)        // 32 float4 per lane
#define CAP 6                       // candidate registers per lane

typedef float nfloat4 __attribute__((ext_vector_type(4)));

__global__ __launch_bounds__(THREADS, 4)
void sparsemax_kernel(const float* __restrict__ x, float* __restrict__ out) {
    const int wave = threadIdx.x >> 6;
    const int lane = threadIdx.x & 63;
    const int row  = blockIdx.x * WPB + wave;
    const float*  __restrict__ xg = x + (size_t)row * NCOL;
    const float4* __restrict__ xr = (const float4*)xg;

    // ---- Pass 1: row max (streaming, coalesced, no barriers ever) ----
    float m = -INFINITY;
#pragma unroll 8
    for (int j = 0; j < F4PW; ++j) {
        float4 q = xr[lane + 64 * j];
        m = fmaxf(m, fmaxf(fmaxf(q.x, q.y), fmaxf(q.z, q.w)));
    }
#pragma unroll
    for (int off = 32; off; off >>= 1) m = fmaxf(m, __shfl_xor(m, off, 64));
    float t = m - 1.0f;   // tau >= max-1 always => support ⊆ {x > max-1}

    // ---- Pass 2: sum/count at t + per-lane candidate bitmask (L2/L3 re-read) ----
    float s = 0.0f;
    unsigned mask[4] = {0u, 0u, 0u, 0u};
#pragma unroll 8
    for (int j = 0; j < F4PW; ++j) {
        float4 q = xr[lane + 64 * j];
        unsigned b = (unsigned)(q.x > t) | ((unsigned)(q.y > t) << 1)
                   | ((unsigned)(q.z > t) << 2) | ((unsigned)(q.w > t) << 3);
        s += (q.x > t ? q.x : 0.0f) + (q.y > t ? q.y : 0.0f)
           + (q.z > t ? q.z : 0.0f) + (q.w > t ? q.w : 0.0f);
        mask[j >> 3] |= b << ((j & 7) * 4);   // j constant after unroll
    }
    int cnt = __popc(mask[0]) + __popc(mask[1]) + __popc(mask[2]) + __popc(mask[3]);
    float kf = (float)cnt;
#pragma unroll
    for (int off = 32; off; off >>= 1) {
        s  += __shfl_xor(s,  off, 64);
        kf += __shfl_xor(kf, off, 64);
    }
    const bool ovf = __any(cnt > CAP);   // wave-uniform fallback flag

    // ---- Extract candidate values into registers (avg ~0.3/lane) ----
    float c0=-INFINITY, c1=-INFINITY, c2=-INFINITY,
          c3=-INFINITY, c4=-INFINITY, c5=-INFINITY;
    if (!ovf) {
        int n = 0;
#pragma unroll
        for (int w = 0; w < 4; ++w) {
            unsigned mm = mask[w];
            while (mm) {
                int p = __builtin_ctz(mm); mm &= mm - 1;
                int j = w * 8 + (p >> 2);
                int comp = p & 3;
                float v = xg[(size_t)(lane + 64 * j) * 4 + comp];
                if      (n == 0) c0 = v;
                else if (n == 1) c1 = v;
                else if (n == 2) c2 = v;
                else if (n == 3) c3 = v;
                else if (n == 4) c4 = v;
                else             c5 = v;
                ++n;
            }
        }
    }

    // ---- Michelot fixed-point: register candidates + shuffles only ----
    float prev_k = kf;
    t = (s - 1.0f) / kf;
    for (int it = 0; it < 32; ++it) {
        float s2 = 0.0f, k2 = 0.0f;
        if (!ovf) {
            if (c0 > t) { s2 += c0; k2 += 1.0f; }
            if (c1 > t) { s2 += c1; k2 += 1.0f; }
            if (c2 > t) { s2 += c2; k2 += 1.0f; }
            if (c3 > t) { s2 += c3; k2 += 1.0f; }
            if (c4 > t) { s2 += c4; k2 += 1.0f; }
            if (c5 > t) { s2 += c5; k2 += 1.0f; }
        } else {
            // Rare: some lane had >CAP candidates; scan the L3-warm row.
#pragma unroll 4
            for (int j = 0; j < F4PW; ++j) {
                float4 q = xr[lane + 64 * j];
                if (q.x > t) { s2 += q.x; k2 += 1.0f; }
                if (q.y > t) { s2 += q.y; k2 += 1.0f; }
                if (q.z > t) { s2 += q.z; k2 += 1.0f; }
                if (q.w > t) { s2 += q.w; k2 += 1.0f; }
            }
        }
#pragma unroll
        for (int off = 32; off; off >>= 1) {
            s2 += __shfl_xor(s2, off, 64);
            k2 += __shfl_xor(k2, off, 64);
        }
        if (k2 == prev_k) break;   // support stable => t is the exact tau
        prev_k = k2;
        t = (s2 - 1.0f) / k2;
    }

    // ---- Pass 3: epilogue out = max(x - tau, 0), nontemporal stores ----
    nfloat4* __restrict__ outr = (nfloat4*)(out + (size_t)row * NCOL);
#pragma unroll 8
    for (int j = 0; j < F4PW; ++j) {
        float4 q = xr[lane + 64 * j];
        nfloat4 o;
        o.x = fmaxf(q.x - t, 0.0f);
        o.y = fmaxf(q.y - t, 0.0f);
        o.z = fmaxf(q.z - t, 0.0f);
        o.w = fmaxf(q.w - t, 0.0f);
        __builtin_nontemporal_store(o, &outr[lane + 64 * j]);
    }
}

extern "C" void kernel_launch(void* const* d_in, const int* in_sizes, int n_in,
                              void* d_out, int out_size, void* d_ws, size_t ws_size,
                              hipStream_t stream) {
    const float* x = (const float*)d_in[0];
    float* out = (float*)d_out;
    sparsemax_kernel<<<ROWS / WPB, THREADS, 0, stream>>>(x, out);
}